// Round 1
// baseline (349.097 us; speedup 1.0000x reference)
//
#include <hip/hip_runtime.h>

// iRPE contextual/transposed PRODUCT:
//   lt[b,h,i,k] = sum_d x[b,h,i,d] * W[h,d,k]      (K=49, tiny GEMV per row)
//   out[b,h,i,j] = lt[b,h,i, bucket[i,j]]           (the 256 MB write)
// Write-BW bound: ~276 MB total HBM traffic -> ~44 us roofline @6.3 TB/s.

constexpr int cB = 8;
constexpr int cH = 8;
constexpr int cL = 1024;
constexpr int cD = 64;
constexpr int cK = 49;

__global__ __launch_bounds__(256) void irpe_kernel(
    const float* __restrict__ x,       // (B,H,L,D)
    const float* __restrict__ W,       // (H,D,K)
    const int*   __restrict__ bucket,  // (L,L), values in [0,49)
    float*       __restrict__ out)     // (B,H,L,L)
{
    __shared__ float xs[cD];
    __shared__ float lt_row[cK];

    // gid -> (i, bh): 64 consecutive blocks share the same bucket row (L2 reuse)
    const int gid = blockIdx.x;
    const int i   = gid >> 6;     // gid / (B*H)
    const int bh  = gid & 63;     // gid % (B*H)
    const int h   = bh & 7;

    const int tid = threadIdx.x;

    // stage x[b,h,i,:] into LDS (64 floats)
    if (tid < cD) {
        xs[tid] = x[((size_t)bh * cL + i) * cD + tid];
    }
    __syncthreads();

    // 49 threads: lt_row[k] = sum_d xs[d] * W[h,d,k]
    if (tid < cK) {
        const float* wp = W + (size_t)h * cD * cK + tid;
        float acc = 0.0f;
        #pragma unroll
        for (int d = 0; d < cD; ++d) {
            acc = fmaf(xs[d], wp[(size_t)d * cK], acc);
        }
        lt_row[tid] = acc;
    }
    __syncthreads();

    // gather + coalesced float4 store: 1024 outputs, 256 threads x 4
    const int4* brow = (const int4*)(bucket + (size_t)i * cL);
    float4*     orow = (float4*)(out + ((size_t)bh * cL + i) * cL);

    const int4 bk = brow[tid];
    float4 o;
    o.x = lt_row[bk.x];
    o.y = lt_row[bk.y];
    o.z = lt_row[bk.z];
    o.w = lt_row[bk.w];
    orow[tid] = o;
}

extern "C" void kernel_launch(void* const* d_in, const int* in_sizes, int n_in,
                              void* d_out, int out_size, void* d_ws, size_t ws_size,
                              hipStream_t stream) {
    const float* x      = (const float*)d_in[0];   // (8,8,1024,64) fp32
    const float* W      = (const float*)d_in[1];   // (8,64,49) fp32
    const int*   bucket = (const int*)d_in[2];     // (1024,1024) int32
    float*       out    = (float*)d_out;           // (8,8,1024,1024) fp32

    const int grid = cB * cH * cL;                 // 65536 blocks
    irpe_kernel<<<grid, 256, 0, stream>>>(x, W, bucket, out);
}

// Round 2
// 320.370 us; speedup vs baseline: 1.0897x; 1.0897x over previous
//
#include <hip/hip_runtime.h>

// iRPE contextual/transposed PRODUCT:
//   lt[b,h,i,k] = sum_d x[b,h,i,d] * W[h,d,k]      (K=49 GEMV per row)
//   out[b,h,i,j] = lt[b,h,i, bucket[i,j]]           (the 256 MB write)
//
// Grid inversion vs round-0: one block per (i, bh-half). Each block writes
// 128 KB (32 rows x 4 KB) so the x-load + GEMV setup (~3K cyc) is amortized
// over ~13K cycles of stores, instead of 4 KB/block where setup dominated.
// Bucket row is loaded ONCE into registers (int4/thread) and reused for all
// 32 output rows.

constexpr int cL = 1024;
constexpr int cD = 64;
constexpr int cK = 49;
constexpr int cBH = 64;   // B*H
constexpr int cHALF = 32; // bh rows per block

__global__ __launch_bounds__(256) void irpe_fused(
    const float* __restrict__ x,       // (B,H,L,D) = (bh, i, d)
    const float* __restrict__ W,       // (H,D,K)
    const int*   __restrict__ bucket,  // (L,L), values in [0,49)
    float*       __restrict__ out)     // (B,H,L,L)
{
    __shared__ float4 xs4[cHALF][cD / 4];   // x[lh][d] as float4, 8 KB
    __shared__ float  lts[cHALF * cK];      // lt values, 6.1 KB

    const int gid  = blockIdx.x;
    const int i    = gid >> 1;              // row of bucket / x
    const int bh0  = (gid & 1) * cHALF;     // which half of the 64 bh rows
    const int tid  = threadIdx.x;

    // ---- Phase A: stage x rows (32 x 256 B, coalesced float4) ----
    const float4* x4 = (const float4*)x;
    #pragma unroll
    for (int r = 0; r < 2; ++r) {
        const int idx = r * 256 + tid;
        const int lh  = idx >> 4;           // 0..31
        const int d4  = idx & 15;           // 0..15
        xs4[lh][d4] = x4[((size_t)(bh0 + lh) * cL + i) * (cD / 4) + d4];
    }

    // bucket row i -> registers, reused for all 32 output rows
    const int4 bk = ((const int4*)(bucket + (size_t)i * cL))[tid];

    __syncthreads();

    // ---- Phase B: lts[lh*49+k] = sum_d xs[lh][d] * W[h,d,k] ----
    // Consecutive lanes -> consecutive k => coalesced W loads (L2-resident).
    // xs reads broadcast (all lanes in a k-run share lh).
    const float* xsf = (const float*)xs4;
    for (int p = tid; p < cHALF * cK; p += 256) {
        const int lh = p / cK;
        const int k  = p - lh * cK;
        const int h  = (bh0 + lh) & 7;
        const float* wp = W + (size_t)h * cD * cK + k;
        const float* xr = xsf + lh * cD;
        float acc = 0.0f;
        #pragma unroll
        for (int d = 0; d < cD; ++d) {
            acc = fmaf(xr[d], wp[(size_t)d * cK], acc);
        }
        lts[p] = acc;
    }
    __syncthreads();

    // ---- Phase C: gather + stream 32 x 4 KB coalesced float4 stores ----
    float4* obase = (float4*)(out + (size_t)bh0 * cL * cL + (size_t)i * cL);
    #pragma unroll 4
    for (int lh = 0; lh < cHALF; ++lh) {
        const float* lrow = lts + lh * cK;
        float4 o;
        o.x = lrow[bk.x];
        o.y = lrow[bk.y];
        o.z = lrow[bk.z];
        o.w = lrow[bk.w];
        obase[(size_t)lh * cL * (cL / 4) + tid] = o;
    }
}

extern "C" void kernel_launch(void* const* d_in, const int* in_sizes, int n_in,
                              void* d_out, int out_size, void* d_ws, size_t ws_size,
                              hipStream_t stream) {
    const float* x      = (const float*)d_in[0];   // (8,8,1024,64) fp32
    const float* W      = (const float*)d_in[1];   // (8,64,49) fp32
    const int*   bucket = (const int*)d_in[2];     // (1024,1024) int32
    float*       out    = (float*)d_out;           // (8,8,1024,1024) fp32

    const int grid = cL * 2;                        // 2048 blocks
    irpe_fused<<<grid, 256, 0, stream>>>(x, W, bucket, out);
}